// Round 5
// baseline (343.704 us; speedup 1.0000x reference)
//
#include <hip/hip_runtime.h>
#include <math.h>

namespace {

constexpr int NROWS = 2048;   // B*T
constexpr int DIN   = 512;
constexpr int DOUT  = 512;
constexpr int HEADS = 4;
constexpr int KDIM  = 512;
constexpr int HALFD = 256;
constexpr int NKEYS = 512;
constexpr int KNN   = 32;

// =================== big-tile f32 NT GEMM body: 128x64, 8x4 micro ==========
// Double-buffered LDS: one barrier per K-step; global load for tile k+2
// issues in iter k (T14), ds_write of tile k+1 overlaps compute of tile k.
// FMA order identical to R4 body -> bit-identical results.
template<int EPI>
__device__ inline void gemm128x64_body(const float* __restrict__ A, int lda,
                                       const float* __restrict__ B, int ldb,
                                       float* __restrict__ C, int ldc,
                                       const float* __restrict__ bias, int K,
                                       int m0, int n0)
{
    __shared__ __align__(16) float as[2][16][132];
    __shared__ __align__(16) float bs[2][16][68];
    const int tid = threadIdx.x;
    const int tx = tid & 15;          // n: 4 cols each
    const int ty = tid >> 4;          // m: 8 rows each
    const int lrA = tid >> 1, lkA = (tid & 1) << 3;
    const int lrB = tid >> 2, lkB = (tid & 3) << 2;
    const float* Ap = A + (size_t)(m0 + lrA) * lda + lkA;
    const float* Bp = B + (size_t)(n0 + lrB) * ldb + lkB;
    float acc[8][4] = {};
    const int NK = K >> 4;

    // prologue: tile 0 -> LDS[0]; prefetch tile 1 -> regs
    float4 a0 = *(const float4*)(Ap);
    float4 a1 = *(const float4*)(Ap + 4);
    float4 b0 = *(const float4*)(Bp);
    as[0][lkA + 0][lrA] = a0.x; as[0][lkA + 1][lrA] = a0.y;
    as[0][lkA + 2][lrA] = a0.z; as[0][lkA + 3][lrA] = a0.w;
    as[0][lkA + 4][lrA] = a1.x; as[0][lkA + 5][lrA] = a1.y;
    as[0][lkA + 6][lrA] = a1.z; as[0][lkA + 7][lrA] = a1.w;
    bs[0][lkB + 0][lrB] = b0.x; bs[0][lkB + 1][lrB] = b0.y;
    bs[0][lkB + 2][lrB] = b0.z; bs[0][lkB + 3][lrB] = b0.w;
    if (NK > 1) {
        a0 = *(const float4*)(Ap + 16);
        a1 = *(const float4*)(Ap + 20);
        b0 = *(const float4*)(Bp + 16);
    }
    __syncthreads();

    for (int k = 0; k < NK; ++k) {
        const int cur = k & 1, nxt = cur ^ 1;
        if (k + 1 < NK) {             // stage tile k+1 (regs -> LDS[nxt])
            as[nxt][lkA + 0][lrA] = a0.x; as[nxt][lkA + 1][lrA] = a0.y;
            as[nxt][lkA + 2][lrA] = a0.z; as[nxt][lkA + 3][lrA] = a0.w;
            as[nxt][lkA + 4][lrA] = a1.x; as[nxt][lkA + 5][lrA] = a1.y;
            as[nxt][lkA + 6][lrA] = a1.z; as[nxt][lkA + 7][lrA] = a1.w;
            bs[nxt][lkB + 0][lrB] = b0.x; bs[nxt][lkB + 1][lrB] = b0.y;
            bs[nxt][lkB + 2][lrB] = b0.z; bs[nxt][lkB + 3][lrB] = b0.w;
        }
        if (k + 2 < NK) {             // issue global load for tile k+2
            a0 = *(const float4*)(Ap + (k + 2) * 16);
            a1 = *(const float4*)(Ap + (k + 2) * 16 + 4);
            b0 = *(const float4*)(Bp + (k + 2) * 16);
        }
        #pragma unroll
        for (int kk = 0; kk < 16; ++kk) {
            const float4 a0v = *(const float4*)&as[cur][kk][ty << 3];
            const float4 a1v = *(const float4*)&as[cur][kk][(ty << 3) + 4];
            const float4 bv  = *(const float4*)&bs[cur][kk][tx << 2];
            const float ar[8] = {a0v.x, a0v.y, a0v.z, a0v.w,
                                 a1v.x, a1v.y, a1v.z, a1v.w};
            const float br[4] = {bv.x, bv.y, bv.z, bv.w};
            #pragma unroll
            for (int i = 0; i < 8; ++i)
                #pragma unroll
                for (int j = 0; j < 4; ++j)
                    acc[i][j] = fmaf(ar[i], br[j], acc[i][j]);
        }
        __syncthreads();
    }

    float4 bb = {0.f, 0.f, 0.f, 0.f};
    if (bias) bb = *(const float4*)(bias + n0 + (tx << 2));
    #pragma unroll
    for (int i = 0; i < 8; ++i) {
        float4 o;
        o.x = acc[i][0] + bb.x; o.y = acc[i][1] + bb.y;
        o.z = acc[i][2] + bb.z; o.w = acc[i][3] + bb.w;
        if (EPI == 1) {
            o.x = o.x / (1.f + expf(-o.x));
            o.y = o.y / (1.f + expf(-o.y));
            o.z = o.z / (1.f + expf(-o.z));
            o.w = o.w / (1.f + expf(-o.w));
        }
        *(float4*)(C + (size_t)(m0 + (ty << 3) + i) * ldc + n0 + (tx << 2)) = o;
    }
}

// q = x @ Wq^T + bq
__global__ __launch_bounds__(256)
void gemm_big(const float* __restrict__ A, int lda,
              const float* __restrict__ B, int ldb,
              float* __restrict__ C, int ldc,
              const float* __restrict__ bias, int K)
{
    gemm128x64_body<0>(A, lda, B, ldb, C, ldc, bias, K,
                       blockIdx.y * 128, blockIdx.x * 64);
}

// z<8: s_z = q_z @ keys_z^T  (K=256)  |  z==8: gate = silu(x@Wsw^T+bsw) (K=512)
__global__ __launch_bounds__(256)
void score_gate_gemm(const float* __restrict__ q, const float* __restrict__ keys,
                     const float* __restrict__ x,
                     const float* __restrict__ Wsw, const float* __restrict__ bsw,
                     float* __restrict__ s, float* __restrict__ gate)
{
    const int z = blockIdx.z;
    if (z < 8)
        gemm128x64_body<0>(q + (z >> 1) * KDIM + (z & 1) * HALFD, HEADS * KDIM,
                           keys + (size_t)z * NKEYS * HALFD, HALFD,
                           s + z * NKEYS, HEADS * 2 * NKEYS, nullptr, HALFD,
                           blockIdx.y * 128, blockIdx.x * 64);
    else
        gemm128x64_body<1>(x, DIN, Wsw, DIN, gate, DOUT, bsw, DIN,
                           blockIdx.y * 128, blockIdx.x * 64);
}

// =================== small-tile f32 NT GEMM: 64x64, 4x4 micro (dbuf) =======
__global__ __launch_bounds__(256)
void gemm_nt(const float* __restrict__ A, int lda,
             const float* __restrict__ B, int ldb,
             float* __restrict__ C, int ldc,
             const float* __restrict__ bias, int K)
{
    __shared__ __align__(16) float as[2][16][68];
    __shared__ __align__(16) float bs[2][16][68];
    const int tid = threadIdx.x;
    const int tx = tid & 15, ty = tid >> 4;
    const int m0 = blockIdx.y * 64, n0 = blockIdx.x * 64;
    const int lrow = tid >> 2;
    const int lk4  = (tid & 3) << 2;
    const float* Ap = A + (size_t)(m0 + lrow) * lda + lk4;
    const float* Bp = B + (size_t)(n0 + lrow) * ldb + lk4;
    float acc[4][4] = {};
    const int NK = K >> 4;

    float4 av = *(const float4*)(Ap);
    float4 bv = *(const float4*)(Bp);
    as[0][lk4 + 0][lrow] = av.x; as[0][lk4 + 1][lrow] = av.y;
    as[0][lk4 + 2][lrow] = av.z; as[0][lk4 + 3][lrow] = av.w;
    bs[0][lk4 + 0][lrow] = bv.x; bs[0][lk4 + 1][lrow] = bv.y;
    bs[0][lk4 + 2][lrow] = bv.z; bs[0][lk4 + 3][lrow] = bv.w;
    if (NK > 1) {
        av = *(const float4*)(Ap + 16);
        bv = *(const float4*)(Bp + 16);
    }
    __syncthreads();

    for (int k = 0; k < NK; ++k) {
        const int cur = k & 1, nxt = cur ^ 1;
        if (k + 1 < NK) {
            as[nxt][lk4 + 0][lrow] = av.x; as[nxt][lk4 + 1][lrow] = av.y;
            as[nxt][lk4 + 2][lrow] = av.z; as[nxt][lk4 + 3][lrow] = av.w;
            bs[nxt][lk4 + 0][lrow] = bv.x; bs[nxt][lk4 + 1][lrow] = bv.y;
            bs[nxt][lk4 + 2][lrow] = bv.z; bs[nxt][lk4 + 3][lrow] = bv.w;
        }
        if (k + 2 < NK) {
            av = *(const float4*)(Ap + (k + 2) * 16);
            bv = *(const float4*)(Bp + (k + 2) * 16);
        }
        #pragma unroll
        for (int kk = 0; kk < 16; ++kk) {
            const float4 a = *(const float4*)&as[cur][kk][ty << 2];
            const float4 b = *(const float4*)&bs[cur][kk][tx << 2];
            const float ar[4] = {a.x, a.y, a.z, a.w};
            const float br[4] = {b.x, b.y, b.z, b.w};
            #pragma unroll
            for (int i = 0; i < 4; ++i)
                #pragma unroll
                for (int j = 0; j < 4; ++j)
                    acc[i][j] = fmaf(ar[i], br[j], acc[i][j]);
        }
        __syncthreads();
    }

    float4 bb = {0.f, 0.f, 0.f, 0.f};
    if (bias) bb = *(const float4*)(bias + n0 + (tx << 2));
    #pragma unroll
    for (int i = 0; i < 4; ++i) {
        float4 o;
        o.x = acc[i][0] + bb.x; o.y = acc[i][1] + bb.y;
        o.z = acc[i][2] + bb.z; o.w = acc[i][3] + bb.w;
        *(float4*)(C + (size_t)(m0 + (ty << 2) + i) * ldc + n0 + (tx << 2)) = o;
    }
}

// =================== two-stage product-key top-k + softmax =================
// (identical to the R2-verified kernel)
__global__ __launch_bounds__(64)
void topk_kernel(const float* __restrict__ s,
                 float* __restrict__ w_out, int* __restrict__ idx_out)
{
    const int nh   = blockIdx.x;
    const int lane = threadIdx.x;
    const int sub  = lane >> 5;
    const int sl   = lane & 31;
    __shared__ float ts[2][KNN];
    __shared__ int   ti[2][KNN];
    const float* sb = s + (size_t)nh * (2 * NKEYS) + sub * NKEYS;

    float v[16];
    #pragma unroll
    for (int i = 0; i < 16; ++i) v[i] = sb[i * 32 + sl];
    unsigned used = 0;
    for (int it = 0; it < KNN; ++it) {
        float bv = -INFINITY; int bi = 0;
        #pragma unroll
        for (int i = 0; i < 16; ++i) {
            const bool ok = !((used >> i) & 1u) && v[i] > bv;
            bv = ok ? v[i] : bv;
            bi = ok ? i : bi;
        }
        float m = bv;
        #pragma unroll
        for (int off = 16; off; off >>= 1) m = fmaxf(m, __shfl_xor(m, off));
        const int cand = (bv == m) ? ((bi << 5) | sl) : 0x7fffffff;
        const unsigned long long bal = __ballot(bv == m);
        const unsigned half = (unsigned)(bal >> (sub << 5));
        int e;
        if (__popc(half) == 1) {
            e = __shfl(cand, (sub << 5) + (__ffs(half) - 1));
        } else {
            int cm = cand;
            #pragma unroll
            for (int off = 16; off; off >>= 1) cm = min(cm, __shfl_xor(cm, off));
            e = cm;
        }
        if (sl == 0) { ts[sub][it] = m; ti[sub][it] = e; }
        if (sl == (e & 31)) used |= 1u << (e >> 5);
    }
    __syncthreads();

    float cv[2]; int cc[2];
    #pragma unroll
    for (int t = 0; t < 2; ++t) {
        const int c = t * 64 + lane;
        int ii = -1, jj = 0, off = 0;
        #pragma unroll
        for (int i = 0; i < 32; ++i) {
            const int cnt = 32 / (i + 1);
            const bool in = (c >= off) && (c < off + cnt);
            ii = in ? i : ii;
            jj = in ? c - off : jj;
            off += cnt;
        }
        if (ii >= 0) { cv[t] = ts[0][ii] + ts[1][jj]; cc[t] = ii * 32 + jj; }
        else         { cv[t] = -INFINITY;             cc[t] = 0x7fffffff;  }
    }

    unsigned used2 = 0;
    float mval = 0.f, myval = -INFINITY;
    int mycombo = 0;
    for (int it = 0; it < KNN; ++it) {
        float bv = -INFINITY; int bc = 0x7fffffff;
        #pragma unroll
        for (int t = 0; t < 2; ++t) {
            const bool live = !((used2 >> t) & 1u);
            const bool better = live &&
                (cv[t] > bv || (cv[t] == bv && cc[t] < bc));
            bv = better ? cv[t] : bv;
            bc = better ? cc[t] : bc;
        }
        float m = bv;
        #pragma unroll
        for (int off = 32; off; off >>= 1) m = fmaxf(m, __shfl_xor(m, off));
        const unsigned long long bal = __ballot(bv == m);
        int combo;
        if (__popcll(bal) == 1) {
            combo = __shfl(bc, (int)(__ffsll(bal) - 1));
        } else {
            unsigned cm = (bv == m) ? (unsigned)bc : 0xffffffffu;
            #pragma unroll
            for (int off = 32; off; off >>= 1) cm = min(cm, __shfl_xor(cm, off));
            combo = (int)cm;
        }
        if (it == 0) mval = m;
        if (lane == it) { myval = m; mycombo = combo; }
        #pragma unroll
        for (int t = 0; t < 2; ++t)
            if (cc[t] == combo) used2 |= 1u << t;
    }

    const float ew = (lane < KNN) ? expf(myval - mval) : 0.f;
    float ssum = ew;
    #pragma unroll
    for (int off = 32; off; off >>= 1) ssum += __shfl_xor(ssum, off);
    if (lane < KNN) {
        const int i1 = ti[0][mycombo >> 5];
        const int i2 = ti[1][mycombo & 31];
        w_out[(size_t)nh * KNN + lane] = ew / ssum;
        idx_out[(size_t)nh * KNN + lane] = i1 * NKEYS + i2;
    }
}

// =================== weighted embedding-bag gather + gate ==================
__global__ __launch_bounds__(256)
void gather_kernel(const float* __restrict__ values,
                   const float* __restrict__ w, const int* __restrict__ idx,
                   const float* __restrict__ gate, float* __restrict__ out0)
{
    const int n = blockIdx.x;
    const int t = threadIdx.x;
    __shared__ float sw[HEADS * KNN];
    __shared__ int   sidx[HEADS * KNN];
    if (t < HEADS * KNN) {
        sw[t]   = w[(size_t)n * HEADS * KNN + t];
        sidx[t] = idx[(size_t)n * HEADS * KNN + t];
    }
    __syncthreads();
    const int d0 = t * 2;
    float2 acc = {0.f, 0.f};
    #pragma unroll 8
    for (int k = 0; k < HEADS * KNN; ++k) {
        const float2 v = *(const float2*)(values + (size_t)sidx[k] * DOUT + d0);
        const float ww = sw[k];
        acc.x = fmaf(ww, v.x, acc.x);
        acc.y = fmaf(ww, v.y, acc.y);
    }
    const float2 g = *(const float2*)(gate + (size_t)n * DOUT + d0);
    acc.x *= g.x;
    acc.y *= g.y;
    *(float2*)(out0 + (size_t)n * DOUT + d0) = acc;
}

}  // namespace

extern "C" void kernel_launch(void* const* d_in, const int* in_sizes, int n_in,
                              void* d_out, int out_size, void* d_ws, size_t ws_size,
                              hipStream_t stream)
{
    const float* x      = (const float*)d_in[0];
    const float* Wq     = (const float*)d_in[1];
    const float* bq     = (const float*)d_in[2];
    const float* keys   = (const float*)d_in[3];
    const float* values = (const float*)d_in[4];
    const float* Wsw    = (const float*)d_in[5];
    const float* bsw    = (const float*)d_in[6];
    const float* Wv     = (const float*)d_in[7];
    const float* bv     = (const float*)d_in[8];
    float* out = (float*)d_out;

    // ws: q 16MB | s 32MB | wsc 1MB | idx 1MB | gate 4MB | out0 4MB
    float* q    = (float*)d_ws;
    float* s    = q + (size_t)NROWS * HEADS * KDIM;
    float* wsc  = s + (size_t)NROWS * HEADS * 2 * NKEYS;
    int*   idxb = (int*)(wsc + (size_t)NROWS * HEADS * KNN);
    float* gate = (float*)(idxb + (size_t)NROWS * HEADS * KNN);
    float* out0 = gate + (size_t)NROWS * DOUT;

    const dim3 blk(256);

    // 1) q = x @ Wq^T + bq            (2048 x 2048, K=512)
    gemm_big<<<dim3(32, 16), blk, 0, stream>>>(
        x, DIN, Wq, DIN, q, HEADS * KDIM, bq, DIN);

    // 2) scores (z<8, K=256) + gate (z==8, K=512) in one launch
    score_gate_gemm<<<dim3(8, 16, 9), blk, 0, stream>>>(
        q, keys, x, Wsw, bsw, s, gate);

    // 3) two-stage top-32 + softmax
    topk_kernel<<<dim3(NROWS * HEADS), dim3(64), 0, stream>>>(s, wsc, idxb);

    // 4) out0 = (sum_k w*values[idx]) * gate
    gather_kernel<<<dim3(NROWS), blk, 0, stream>>>(values, wsc, idxb, gate, out0);

    // 5) out = out0 @ Wv^T + bv
    gemm_nt<<<dim3(8, 32), blk, 0, stream>>>(
        out0, DOUT, Wv, DOUT, out, DOUT, bv, DOUT);
}